// Round 5
// baseline (907.109 us; speedup 1.0000x reference)
//
#include <hip/hip_runtime.h>

#define VQ_EPS 1e-12f
#define VQ_MARGIN 0.02f          // >> 60x the bf16 dot-error sigma (~3e-4)

typedef short bf16x8 __attribute__((ext_vector_type(8)));   // 8 bf16 bit-patterns = 4 VGPRs
typedef float f32x4  __attribute__((ext_vector_type(4)));

static __device__ __forceinline__ unsigned short f2bf(float f) {
    unsigned u = __float_as_uint(f);
    u += 0x7fffu + ((u >> 16) & 1u);     // RNE
    return (unsigned short)(u >> 16);
}

// Prep kernel: normalize codebook rows (fp32, mirrors F.normalize), emit:
//   cbn  [512][64] fp32      -- exact rescore + codes-gather epilogue
//   cbB  [32 ntile][2 kstep][64 lane][8] bf16 -- B-fragment-linear for
//        mfma_f32_16x16x32_bf16: value = cb[code=ntile*16+(lane&15)][c=kstep*32+(lane>>4)*8+j]
//   kn2  [512] fp32          -- sum(cbn^2) AFTER normalization (reference rounding)
//   kn2p [512] fp32          -- kn2 + 2.0f (keeps approx scores > 0 for uint packing)
__global__ __launch_bounds__(64) void cb_prep_kernel(const float* __restrict__ cb,
                                                     float* __restrict__ cbn,
                                                     unsigned short* __restrict__ cbB,
                                                     float* __restrict__ kn2,
                                                     float* __restrict__ kn2p) {
    const int k = blockIdx.x;       // 512 codes
    const int c = threadIdx.x;      // 64 channels
    float v = cb[k * 64 + c];
    float s = v * v;
    #pragma unroll
    for (int off = 32; off > 0; off >>= 1) s += __shfl_xor(s, off, 64);
    float n = sqrtf(s);
    float cn = v / fmaxf(n, VQ_EPS);
    cbn[k * 64 + c] = cn;

    const int ntile = k >> 4, col = k & 15;
    const int ks = c >> 5, quad = (c >> 3) & 3, j = c & 7;
    cbB[(((ntile * 2 + ks) * 64) + quad * 16 + col) * 8 + j] = f2bf(cn);

    float s2 = cn * cn;
    #pragma unroll
    for (int off = 32; off > 0; off >>= 1) s2 += __shfl_xor(s2, off, 64);
    if (c == 0) { kn2[k] = s2; kn2p[k] = s2 + 2.0f; }
}

// Main kernel: block = 256 thr (4 waves) = 64 pixels (one (b,h) row, w=0..63).
// Each wave: 16 pixels x all 512 codes via mfma_f32_16x16x32_bf16, dots kept
// in 128 VGPRs; approx scores packed (floatbits & ~0x1FF)|k -> v_min_u32
// argmin with smallest-k tie-break; candidate pass collects codes within
// 2*margin; fp32 rescore (exact R1 formula) resolves multi-candidate pixels.
__global__ __launch_bounds__(256, 2) void vq_mfma_kernel(const float* __restrict__ x,
                                                         const float* __restrict__ cbn,
                                                         const unsigned short* __restrict__ cbB,
                                                         const float* __restrict__ kn2,
                                                         const float* __restrict__ kn2p,
                                                         float* __restrict__ codes,
                                                         float* __restrict__ idxout) {
    __shared__ float4 sB4[4096];          // 64 KB codebook B-fragments
    __shared__ float  skn2p[512];
    __shared__ int    scnt[64];
    __shared__ int    slist[64][8];
    __shared__ int    sbest[64];

    const int t    = threadIdx.x;
    const int lane = t & 63;
    const int wid  = t >> 6;
    const int col  = lane & 15;
    const int quad = lane >> 4;

    // ---- stage codebook fragments + kn2p into LDS (coalesced dwordx4) ----
    {
        const float4* srcB4 = (const float4*)cbB;
        #pragma unroll
        for (int q = 0; q < 16; ++q) sB4[t + 256 * q] = srcB4[t + 256 * q];
        skn2p[t]       = kn2p[t];
        skn2p[t + 256] = kn2p[t + 256];
        if (t < 64) scnt[t] = 0;
    }
    __syncthreads();

    // ---- A fragments: this wave's 16 pixels, straight from global ----
    const int pbase = blockIdx.x * 64;                 // block pixel base
    const int b = pbase >> 12;
    const int h = (pbase >> 6) & 63;
    const float* xblk = x + ((size_t)b << 18) + (h << 6);   // + c*4096 + w
    const int wpix = wid * 16 + col;                   // lane's pixel (w coord)

    float xv[16];
    #pragma unroll
    for (int ks = 0; ks < 2; ++ks)
        #pragma unroll
        for (int j = 0; j < 8; ++j)
            xv[ks * 8 + j] = xblk[(size_t)(ks * 32 + quad * 8 + j) * 4096 + wpix];

    float ssp = 0.0f;
    #pragma unroll
    for (int i = 0; i < 16; ++i) ssp = fmaf(xv[i], xv[i], ssp);
    ssp += __shfl_xor(ssp, 16);      // channels partition across quads
    ssp += __shfl_xor(ssp, 32);
    const float inv = 1.0f / fmaxf(sqrtf(ssp), VQ_EPS);
    const float m2  = -2.0f * inv;   // approx-score scale for lane's pixel (=col)
    float m2r[4];
    #pragma unroll
    for (int r = 0; r < 4; ++r) m2r[r] = __shfl(m2, quad * 4 + r);  // per C-row

    bf16x8 afrag[2];
    #pragma unroll
    for (int ks = 0; ks < 2; ++ks)
        #pragma unroll
        for (int j = 0; j < 8; ++j)
            ((unsigned short*)&afrag[ks])[j] = f2bf(xv[ks * 8 + j]);

    // ---- MFMA scan: 32 code-tiles x 2 ksteps; packed running argmin ----
    const bf16x8* sBf = (const bf16x8*)sB4;
    f32x4 dots[32];
    unsigned run[4] = {0xFFFFFFFFu, 0xFFFFFFFFu, 0xFFFFFFFFu, 0xFFFFFFFFu};

    #pragma unroll
    for (int nt = 0; nt < 32; ++nt) {
        bf16x8 b0 = sBf[(nt * 2 + 0) * 64 + lane];     // ds_read_b128, conflict-free
        bf16x8 b1 = sBf[(nt * 2 + 1) * 64 + lane];
        f32x4 c = {0.0f, 0.0f, 0.0f, 0.0f};
        c = __builtin_amdgcn_mfma_f32_16x16x32_bf16(afrag[0], b0, c, 0, 0, 0);
        c = __builtin_amdgcn_mfma_f32_16x16x32_bf16(afrag[1], b1, c, 0, 0, 0);
        dots[nt] = c;
        const float    kn   = skn2p[nt * 16 + col];
        const unsigned kidx = (unsigned)(nt * 16 + col);
        #pragma unroll
        for (int r = 0; r < 4; ++r) {
            float s = fmaf(m2r[r], c[r], kn);          // in [~0.8, 5.2] -> uint-orderable
            unsigned key = (__float_as_uint(s) & 0xFFFFFE00u) | kidx;
            run[r] = min(run[r], key);
        }
    }

    // ---- cross-lane min within each 16-lane group (cols of the tile) ----
    float thr[4];
    #pragma unroll
    for (int r = 0; r < 4; ++r) {
        unsigned v = run[r];
        v = min(v, (unsigned)__shfl_xor((int)v, 1));
        v = min(v, (unsigned)__shfl_xor((int)v, 2));
        v = min(v, (unsigned)__shfl_xor((int)v, 4));
        v = min(v, (unsigned)__shfl_xor((int)v, 8));
        thr[r] = __uint_as_float(v & 0xFFFFFE00u) + 2.0f * VQ_MARGIN;
    }

    // ---- candidate pass over stored dots ----
    #pragma unroll
    for (int nt = 0; nt < 32; ++nt) {
        const float kn   = skn2p[nt * 16 + col];
        const int   kidx = nt * 16 + col;
        #pragma unroll
        for (int r = 0; r < 4; ++r) {
            float s = fmaf(m2r[r], dots[nt][r], kn);   // bit-identical to pass 1
            if (s <= thr[r]) {
                int pix = wid * 16 + quad * 4 + r;     // block-local pixel
                int pos = atomicAdd(&scnt[pix], 1);
                if (pos < 8) slist[pix][pos] = kidx;
            }
        }
    }
    __syncthreads();

    // ---- exact fp32 rescore (R1 formula/order) for multi-candidate pixels ----
    if (t < 64) {
        const int cnt = scnt[t];
        int bk;
        if (cnt == 1) {
            bk = slist[t][0];
        } else {
            const float* xp = xblk + t;
            float ss = 0.0f;
            for (int c = 0; c < 64; ++c) { float a = xp[(size_t)c * 4096]; ss = fmaf(a, a, ss); }
            const float inv2 = 1.0f / fmaxf(sqrtf(ss), VQ_EPS);
            const float mm2  = -2.0f * inv2;
            float best = 3.0e38f; bk = 0x7fffffff;
            if (cnt <= 8) {
                for (int i = 0; i < cnt; ++i) {
                    int k = slist[t][i];
                    const float* cr = cbn + (size_t)k * 64;
                    float dot = 0.0f;
                    for (int c = 0; c < 64; ++c) dot = fmaf(xp[(size_t)c * 4096], cr[c], dot);
                    float s = fmaf(mm2, dot, kn2[k]);
                    if (s < best || (s == best && k < bk)) { best = s; bk = k; }
                }
            } else {   // pathological overflow: exact full scan, ascending k
                for (int k = 0; k < 512; ++k) {
                    const float* cr = cbn + (size_t)k * 64;
                    float dot = 0.0f;
                    for (int c = 0; c < 64; ++c) dot = fmaf(xp[(size_t)c * 4096], cr[c], dot);
                    float s = fmaf(mm2, dot, kn2[k]);
                    if (s < best) { best = s; bk = k; }
                }
            }
        }
        sbest[t] = bk;
        idxout[pbase + t] = (float)bk;
    }
    __syncthreads();

    // ---- epilogue: codes[b, :, h, w] = cbn[bestk, :] ----
    {
        const int w  = t & 63;
        const int cq = t >> 6;                          // channel quarter
        const int bk = sbest[w];
        const float4* crow = (const float4*)(cbn + (size_t)bk * 64) + cq * 4;
        float* cp = codes + ((size_t)b << 18) + (h << 6) + w;
        #pragma unroll
        for (int q = 0; q < 4; ++q) {
            float4 v = crow[q];
            const int c0 = cq * 16 + q * 4;
            cp[(size_t)(c0 + 0) * 4096] = v.x;
            cp[(size_t)(c0 + 1) * 4096] = v.y;
            cp[(size_t)(c0 + 2) * 4096] = v.z;
            cp[(size_t)(c0 + 3) * 4096] = v.w;
        }
    }
}

extern "C" void kernel_launch(void* const* d_in, const int* in_sizes, int n_in,
                              void* d_out, int out_size, void* d_ws, size_t ws_size,
                              hipStream_t stream) {
    const float* x  = (const float*)d_in[0];   // [32,64,64,64] fp32
    const float* cb = (const float*)d_in[1];   // [512,64] fp32

    float*          cbn  = (float*)d_ws;                       // 128 KB
    unsigned short* cbB  = (unsigned short*)(cbn + 512 * 64);  // 64 KB (frag-linear bf16)
    float*          kn2  = (float*)(cbB + 32768);              // 2 KB
    float*          kn2p = kn2 + 512;                          // 2 KB

    float* codes  = (float*)d_out;                             // 32*64*64*64 floats
    float* idxout = codes + (size_t)32 * 64 * 64 * 64;         // 131072 floats

    cb_prep_kernel<<<512, 64, 0, stream>>>(cb, cbn, cbB, kn2, kn2p);
    vq_mfma_kernel<<<2048, 256, 0, stream>>>(x, cbn, cbB, kn2, kn2p, codes, idxout);
}

// Round 6
// 158.111 us; speedup vs baseline: 5.7372x; 5.7372x over previous
//
#include <hip/hip_runtime.h>

#define VQ_EPS    1e-12f
#define VQ_WINDOW 0.01f     // >= 2 * 10-sigma of the bf16 per-score error (~5e-4 sigma)
#define VQ_CAP    12

typedef short bf16x8 __attribute__((ext_vector_type(8)));   // 8 bf16 bit-patterns = 4 VGPRs
typedef float f32x4  __attribute__((ext_vector_type(4)));

static __device__ __forceinline__ unsigned short f2bf(float f) {
    unsigned u = __float_as_uint(f);
    u += 0x7fffu + ((u >> 16) & 1u);     // RNE
    return (unsigned short)(u >> 16);
}

// Order-preserving float->uint map (handles negative scores).
static __device__ __forceinline__ unsigned f2ord(float f) {
    unsigned b = __float_as_uint(f);
    return (b & 0x80000000u) ? ~b : (b | 0x80000000u);
}

// Prep kernel: normalize codebook rows (fp32, mirrors F.normalize), emit:
//   cbn  [512][64] fp32      -- exact rescore + codes-gather epilogue
//   cbB  [32 ntile][2 kstep][64 lane][8] bf16 -- B-fragment-linear for
//        mfma_f32_16x16x32_bf16 (layout proven correct in R5, absmax=0)
//   kn2  [512] fp32          -- sum(cbn^2) AFTER normalization (reference rounding)
//   kn2p [512] fp32          -- kn2 + 2.0f (keeps approx scores > 0 for uint packing)
__global__ __launch_bounds__(64) void cb_prep_kernel(const float* __restrict__ cb,
                                                     float* __restrict__ cbn,
                                                     unsigned short* __restrict__ cbB,
                                                     float* __restrict__ kn2,
                                                     float* __restrict__ kn2p) {
    const int k = blockIdx.x;       // 512 codes
    const int c = threadIdx.x;      // 64 channels
    float v = cb[k * 64 + c];
    float s = v * v;
    #pragma unroll
    for (int off = 32; off > 0; off >>= 1) s += __shfl_xor(s, off, 64);
    float n = sqrtf(s);
    float cn = v / fmaxf(n, VQ_EPS);
    cbn[k * 64 + c] = cn;

    const int ntile = k >> 4, col = k & 15;
    const int ks = c >> 5, quad = (c >> 3) & 3, j = c & 7;
    cbB[(((ntile * 2 + ks) * 64) + quad * 16 + col) * 8 + j] = f2bf(cn);

    float s2 = cn * cn;
    #pragma unroll
    for (int off = 32; off > 0; off >>= 1) s2 += __shfl_xor(s2, off, 64);
    if (c == 0) { kn2[k] = s2; kn2p[k] = s2 + 2.0f; }
}

// Main kernel: block = 256 thr (4 waves) = 64 pixels (one (b,h) row).
// Pass 1: MFMA scan over 512 codes -> packed approx argmin per pixel.
// Pass 2: identical MFMA scan recomputed (no dots storage -> no spill);
//         codes within VQ_WINDOW of the approx min go to a per-pixel list.
// Pass 3: exact fp32 rescore (R1 arithmetic order) of candidates, 4 thr/pixel,
//         exact argmin via 64-bit LDS atomicMin (score bits | k).
__global__ __launch_bounds__(256) void vq_mfma_kernel(const float* __restrict__ x,
                                                      const float* __restrict__ cbn,
                                                      const unsigned short* __restrict__ cbB,
                                                      const float* __restrict__ kn2,
                                                      const float* __restrict__ kn2p,
                                                      float* __restrict__ codes,
                                                      float* __restrict__ idxout) {
    __shared__ float4 sB4[4096];          // 64 KB codebook B-fragments
    __shared__ float  skn2p[512];
    __shared__ int    scnt[64];
    __shared__ int    slist[64][VQ_CAP];
    __shared__ unsigned long long spack[64];
    __shared__ float  sm2[64];
    __shared__ int    sbest[64];

    const int t    = threadIdx.x;
    const int lane = t & 63;
    const int wid  = t >> 6;
    const int col  = lane & 15;
    const int quad = lane >> 4;

    // ---- stage codebook fragments + kn2p into LDS ----
    {
        const float4* srcB4 = (const float4*)cbB;
        #pragma unroll
        for (int q = 0; q < 16; ++q) sB4[t + 256 * q] = srcB4[t + 256 * q];
        skn2p[t]       = kn2p[t];
        skn2p[t + 256] = kn2p[t + 256];
        if (t < 64) { scnt[t] = 0; spack[t] = 0xFFFFFFFFFFFFFFFFull; }
    }
    __syncthreads();

    // ---- A fragments: this wave's 16 pixels, straight from global ----
    const int pbase = blockIdx.x * 64;                 // block pixel base
    const int b = pbase >> 12;
    const int h = (pbase >> 6) & 63;
    const float* xblk = x + ((size_t)b << 18) + (h << 6);   // + c*4096 + w
    const int wpix = wid * 16 + col;                   // lane's pixel (w coord)

    float xv[16];
    #pragma unroll
    for (int ks = 0; ks < 2; ++ks)
        #pragma unroll
        for (int j = 0; j < 8; ++j)
            xv[ks * 8 + j] = xblk[(size_t)(ks * 32 + quad * 8 + j) * 4096 + wpix];

    float ssp = 0.0f;
    #pragma unroll
    for (int i = 0; i < 16; ++i) ssp = fmaf(xv[i], xv[i], ssp);
    ssp += __shfl_xor(ssp, 16);      // channels partition across quads
    ssp += __shfl_xor(ssp, 32);
    const float inv = 1.0f / fmaxf(sqrtf(ssp), VQ_EPS);
    const float m2a = -2.0f * inv;   // approx-score scale for lane's pixel (=col)
    float m2r[4];
    #pragma unroll
    for (int r = 0; r < 4; ++r) m2r[r] = __shfl(m2a, quad * 4 + r);  // per C-row

    bf16x8 afrag[2];
    #pragma unroll
    for (int ks = 0; ks < 2; ++ks)
        #pragma unroll
        for (int j = 0; j < 8; ++j)
            ((unsigned short*)&afrag[ks])[j] = f2bf(xv[ks * 8 + j]);

    const bf16x8* sBf = (const bf16x8*)sB4;

    // ---- pass 1: MFMA scan, packed running approx argmin ----
    unsigned run[4] = {0xFFFFFFFFu, 0xFFFFFFFFu, 0xFFFFFFFFu, 0xFFFFFFFFu};
    #pragma unroll
    for (int nt = 0; nt < 32; ++nt) {
        bf16x8 b0 = sBf[(nt * 2 + 0) * 64 + lane];
        bf16x8 b1 = sBf[(nt * 2 + 1) * 64 + lane];
        f32x4 c = {0.0f, 0.0f, 0.0f, 0.0f};
        c = __builtin_amdgcn_mfma_f32_16x16x32_bf16(afrag[0], b0, c, 0, 0, 0);
        c = __builtin_amdgcn_mfma_f32_16x16x32_bf16(afrag[1], b1, c, 0, 0, 0);
        const float    kn   = skn2p[nt * 16 + col];
        const unsigned kidx = (unsigned)(nt * 16 + col);
        #pragma unroll
        for (int r = 0; r < 4; ++r) {
            float s = fmaf(m2r[r], c[r], kn);          // in [~0.6, 5.2] -> uint-orderable
            unsigned key = (__float_as_uint(s) & 0xFFFFFE00u) | kidx;
            run[r] = min(run[r], key);
        }
    }

    // ---- threshold: cross-lane min within each 16-lane col group ----
    float thr[4];
    #pragma unroll
    for (int r = 0; r < 4; ++r) {
        unsigned v = run[r];
        v = min(v, (unsigned)__shfl_xor((int)v, 1));
        v = min(v, (unsigned)__shfl_xor((int)v, 2));
        v = min(v, (unsigned)__shfl_xor((int)v, 4));
        v = min(v, (unsigned)__shfl_xor((int)v, 8));
        thr[r] = __uint_as_float(v & 0xFFFFFE00u) + VQ_WINDOW;
    }

    // ---- pass 2: recompute scan (bit-identical), collect candidates ----
    #pragma unroll
    for (int nt = 0; nt < 32; ++nt) {
        bf16x8 b0 = sBf[(nt * 2 + 0) * 64 + lane];
        bf16x8 b1 = sBf[(nt * 2 + 1) * 64 + lane];
        f32x4 c = {0.0f, 0.0f, 0.0f, 0.0f};
        c = __builtin_amdgcn_mfma_f32_16x16x32_bf16(afrag[0], b0, c, 0, 0, 0);
        c = __builtin_amdgcn_mfma_f32_16x16x32_bf16(afrag[1], b1, c, 0, 0, 0);
        const float kn   = skn2p[nt * 16 + col];
        const int   kidx = nt * 16 + col;
        #pragma unroll
        for (int r = 0; r < 4; ++r) {
            float s = fmaf(m2r[r], c[r], kn);
            if (s <= thr[r]) {
                int pix = wid * 16 + quad * 4 + r;     // block-local pixel
                int pos = atomicAdd(&scnt[pix], 1);
                if (pos < VQ_CAP) slist[pix][pos] = kidx;
            }
        }
    }
    __syncthreads();

    // ---- exact per-pixel scale m2 (R1 arithmetic: sequential ascending c) ----
    if (t < 64) {
        const float* xp = xblk + t;
        float ss = 0.0f;
        #pragma unroll 8
        for (int c = 0; c < 64; ++c) { float a = xp[(size_t)c * 4096]; ss = fmaf(a, a, ss); }
        sm2[t] = -2.0f * (1.0f / fmaxf(sqrtf(ss), VQ_EPS));
    }
    __syncthreads();

    // ---- exact fp32 rescore: 4 threads per pixel, <=3 candidates each ----
    {
        const int pix = t >> 2;
        const int i0  = t & 3;
        const int cnt = min(scnt[pix], VQ_CAP);
        const float* xp = xblk + pix;
        const float mm2 = sm2[pix];
        for (int i = i0; i < cnt; i += 4) {
            const int k = slist[pix][i];
            const float* cr = cbn + (size_t)k * 64;
            float dot = 0.0f;
            #pragma unroll 8
            for (int c = 0; c < 64; ++c) dot = fmaf(xp[(size_t)c * 4096], cr[c], dot);
            float s = fmaf(mm2, dot, kn2[k]);          // exact R1 formula/order
            unsigned long long key = ((unsigned long long)f2ord(s) << 32) | (unsigned)k;
            atomicMin(&spack[pix], key);
        }
    }

    // ---- overflow (statistically dead): cooperative exact full scan ----
    for (int pix = 0; pix < 64; ++pix) {
        if (scnt[pix] > VQ_CAP) {
            const float* xp = xblk + pix;
            const float mm2 = sm2[pix];
            for (int k = t; k < 512; k += 256) {
                const float* cr = cbn + (size_t)k * 64;
                float dot = 0.0f;
                for (int c = 0; c < 64; ++c) dot = fmaf(xp[(size_t)c * 4096], cr[c], dot);
                float s = fmaf(mm2, dot, kn2[k]);
                unsigned long long key = ((unsigned long long)f2ord(s) << 32) | (unsigned)k;
                atomicMin(&spack[pix], key);
            }
        }
    }
    __syncthreads();

    if (t < 64) {
        int bk = (int)(spack[t] & 0xFFFFFFFFull);
        sbest[t] = bk;
        idxout[pbase + t] = (float)bk;
    }
    __syncthreads();

    // ---- epilogue: codes[b, :, h, w] = cbn[bestk, :] ----
    {
        const int w  = t & 63;
        const int cq = t >> 6;                          // channel quarter
        const int bk = sbest[w];
        const float4* crow = (const float4*)(cbn + (size_t)bk * 64) + cq * 4;
        float* cp = codes + ((size_t)b << 18) + (h << 6) + w;
        #pragma unroll
        for (int q = 0; q < 4; ++q) {
            float4 v = crow[q];
            const int c0 = cq * 16 + q * 4;
            cp[(size_t)(c0 + 0) * 4096] = v.x;
            cp[(size_t)(c0 + 1) * 4096] = v.y;
            cp[(size_t)(c0 + 2) * 4096] = v.z;
            cp[(size_t)(c0 + 3) * 4096] = v.w;
        }
    }
}

extern "C" void kernel_launch(void* const* d_in, const int* in_sizes, int n_in,
                              void* d_out, int out_size, void* d_ws, size_t ws_size,
                              hipStream_t stream) {
    const float* x  = (const float*)d_in[0];   // [32,64,64,64] fp32
    const float* cb = (const float*)d_in[1];   // [512,64] fp32

    float*          cbn  = (float*)d_ws;                       // 128 KB
    unsigned short* cbB  = (unsigned short*)(cbn + 512 * 64);  // 64 KB (frag-linear bf16)
    float*          kn2  = (float*)(cbB + 32768);              // 2 KB
    float*          kn2p = kn2 + 512;                          // 2 KB

    float* codes  = (float*)d_out;                             // 32*64*64*64 floats
    float* idxout = codes + (size_t)32 * 64 * 64 * 64;         // 131072 floats

    cb_prep_kernel<<<512, 64, 0, stream>>>(cb, cbn, cbB, kn2, kn2p);
    vq_mfma_kernel<<<2048, 256, 0, stream>>>(x, cbn, cbB, kn2, kn2p, codes, idxout);
}

// Round 8
// 134.466 us; speedup vs baseline: 6.7460x; 1.1758x over previous
//
#include <hip/hip_runtime.h>

#define VQ_EPS    1e-12f
#define VQ_WINDOW 0.01f     // >= ~10 sigma of the bf16 score error; proven R6/R7 (absmax 0)
#define VQ_CAP    12

typedef short bf16x8 __attribute__((ext_vector_type(8)));   // 8 bf16 bit-patterns = 4 VGPRs
typedef float f32x4  __attribute__((ext_vector_type(4)));

static __device__ __forceinline__ unsigned short f2bf(float f) {
    unsigned u = __float_as_uint(f);
    u += 0x7fffu + ((u >> 16) & 1u);     // RNE
    return (unsigned short)(u >> 16);
}

// Order-preserving float->uint map (handles negative exact scores).
static __device__ __forceinline__ unsigned f2ord(float f) {
    unsigned b = __float_as_uint(f);
    return (b & 0x80000000u) ? ~b : (b | 0x80000000u);
}

// Prep kernel: normalize codebook rows (fp32, mirrors F.normalize), emit:
//   cbn  [512][64] fp32      -- exact rescore + codes-gather epilogue
//   cbB  [32 ntile][2 kstep][64 lane][8] bf16 -- B-fragment-linear for
//        mfma_f32_16x16x32_bf16 (layout proven correct R5-R7)
//   kn2  [512] fp32          -- sum(cbn^2) AFTER normalization (reference rounding)
//   kn2p [512] fp32          -- kn2 + 2.0f (keeps approx scores > 0 for uint packing)
__global__ __launch_bounds__(64) void cb_prep_kernel(const float* __restrict__ cb,
                                                     float* __restrict__ cbn,
                                                     unsigned short* __restrict__ cbB,
                                                     float* __restrict__ kn2,
                                                     float* __restrict__ kn2p) {
    const int k = blockIdx.x;       // 512 codes
    const int c = threadIdx.x;      // 64 channels
    float v = cb[k * 64 + c];
    float s = v * v;
    #pragma unroll
    for (int off = 32; off > 0; off >>= 1) s += __shfl_xor(s, off, 64);
    float n = sqrtf(s);
    float cn = v / fmaxf(n, VQ_EPS);
    cbn[k * 64 + c] = cn;

    const int ntile = k >> 4, col = k & 15;
    const int ks = c >> 5, quad = (c >> 3) & 3, j = c & 7;
    cbB[(((ntile * 2 + ks) * 64) + quad * 16 + col) * 8 + j] = f2bf(cn);

    float s2 = cn * cn;
    #pragma unroll
    for (int off = 32; off > 0; off >>= 1) s2 += __shfl_xor(s2, off, 64);
    if (c == 0) { kn2[k] = s2; kn2p[k] = s2 + 2.0f; }
}

// Main kernel: 512 blocks x 256 thr; block handles 4 pixel-rows of 64.
// Codebook staged into LDS once. Per row: MFMA pass1 (approx argmin via packed
// key), bit-identical pass2 collects candidates within VQ_WINDOW, per-lane
// exact fp32 rescore (4 lanes/pixel, global x reads, 64-bit LDS atomicMin).
// ALL cross-lane shfls live in uniform code; divergent regions contain only
// per-lane memory ops and LDS atomics. 3 barriers/row make every LDS handoff
// block-visible (no reliance on in-wave ordering).
__global__ __launch_bounds__(256) void vq_mfma_kernel(const float* __restrict__ x,
                                                      const float* __restrict__ cbn,
                                                      const unsigned short* __restrict__ cbB,
                                                      const float* __restrict__ kn2,
                                                      const float* __restrict__ kn2p,
                                                      float* __restrict__ codes,
                                                      float* __restrict__ idxout) {
    __shared__ float4 sB4[4096];          // 64 KB codebook B-fragments
    __shared__ float  skn2p[512];
    __shared__ int    scnt[64];
    __shared__ int    slist[64][VQ_CAP];
    __shared__ unsigned long long spack[64];

    const int t    = threadIdx.x;
    const int lane = t & 63;
    const int wid  = t >> 6;
    const int col  = lane & 15;
    const int quad = lane >> 4;
    const int wpix = wid * 16 + col;      // col-group's pixel (w coordinate)

    // ---- stage codebook fragments + kn2p into LDS (once per block) ----
    {
        const float4* srcB4 = (const float4*)cbB;
        #pragma unroll
        for (int q = 0; q < 16; ++q) sB4[t + 256 * q] = srcB4[t + 256 * q];
        skn2p[t]       = kn2p[t];
        skn2p[t + 256] = kn2p[t + 256];
    }
    __syncthreads();

    const bf16x8* sBf = (const bf16x8*)sB4;
    const int row0 = blockIdx.x * 4;

    for (int rr = 0; rr < 4; ++rr) {
        const int rowid = row0 + rr;              // 0..2047 = (b,h)
        const int b = rowid >> 6;
        const int h = rowid & 63;
        const float* xblk = x + ((size_t)b << 18) + (h << 6);   // + c*4096 + w

        if (quad == 0) { scnt[wpix] = 0; spack[wpix] = 0xFFFFFFFFFFFFFFFFull; }

        // ---- A fragments: 16 channels of this lane's pixel, from global ----
        float xv[16];
        #pragma unroll
        for (int ks = 0; ks < 2; ++ks)
            #pragma unroll
            for (int j = 0; j < 8; ++j)
                xv[ks * 8 + j] = xblk[(size_t)(ks * 32 + quad * 8 + j) * 4096 + wpix];

        float ssp = 0.0f;
        #pragma unroll
        for (int i = 0; i < 16; ++i) ssp = fmaf(xv[i], xv[i], ssp);
        ssp += __shfl_xor(ssp, 16);      // uniform code: all 64 lanes execute
        ssp += __shfl_xor(ssp, 32);
        const float m2a = -2.0f * (1.0f / fmaxf(sqrtf(ssp), VQ_EPS));
        float m2r[4];
        #pragma unroll
        for (int r = 0; r < 4; ++r) m2r[r] = __shfl(m2a, quad * 4 + r);  // uniform
        const float m2P = __shfl(m2a, lane >> 2);   // uniform: m2 of rescore pixel

        bf16x8 afrag[2];
        #pragma unroll
        for (int ks = 0; ks < 2; ++ks)
            #pragma unroll
            for (int j = 0; j < 8; ++j)
                ((unsigned short*)&afrag[ks])[j] = f2bf(xv[ks * 8 + j]);

        // ---- pass 1: MFMA scan, packed running approx argmin ----
        unsigned run[4] = {0xFFFFFFFFu, 0xFFFFFFFFu, 0xFFFFFFFFu, 0xFFFFFFFFu};
        #pragma unroll
        for (int nt = 0; nt < 32; ++nt) {
            bf16x8 b0 = sBf[(nt * 2 + 0) * 64 + lane];
            bf16x8 b1 = sBf[(nt * 2 + 1) * 64 + lane];
            f32x4 c = {0.0f, 0.0f, 0.0f, 0.0f};
            c = __builtin_amdgcn_mfma_f32_16x16x32_bf16(afrag[0], b0, c, 0, 0, 0);
            c = __builtin_amdgcn_mfma_f32_16x16x32_bf16(afrag[1], b1, c, 0, 0, 0);
            const float    kn   = skn2p[nt * 16 + col];
            const unsigned kidx = (unsigned)(nt * 16 + col);
            #pragma unroll
            for (int r = 0; r < 4; ++r) {
                float s = fmaf(m2r[r], c[r], kn);      // in (~0.6, 5.2) -> uint-orderable
                unsigned key = (__float_as_uint(s) & 0xFFFFFE00u) | kidx;
                run[r] = min(run[r], key);
            }
        }

        // ---- threshold: cross-lane min within each 16-lane col group (uniform) ----
        float thr[4];
        #pragma unroll
        for (int r = 0; r < 4; ++r) {
            unsigned v = run[r];
            v = min(v, (unsigned)__shfl_xor((int)v, 1));
            v = min(v, (unsigned)__shfl_xor((int)v, 2));
            v = min(v, (unsigned)__shfl_xor((int)v, 4));
            v = min(v, (unsigned)__shfl_xor((int)v, 8));
            thr[r] = __uint_as_float(v & 0xFFFFFE00u) + VQ_WINDOW;
        }

        // ---- pass 2: bit-identical recompute, collect candidates ----
        #pragma unroll
        for (int nt = 0; nt < 32; ++nt) {
            bf16x8 b0 = sBf[(nt * 2 + 0) * 64 + lane];
            bf16x8 b1 = sBf[(nt * 2 + 1) * 64 + lane];
            f32x4 c = {0.0f, 0.0f, 0.0f, 0.0f};
            c = __builtin_amdgcn_mfma_f32_16x16x32_bf16(afrag[0], b0, c, 0, 0, 0);
            c = __builtin_amdgcn_mfma_f32_16x16x32_bf16(afrag[1], b1, c, 0, 0, 0);
            const float kn   = skn2p[nt * 16 + col];
            const int   kidx = nt * 16 + col;
            #pragma unroll
            for (int r = 0; r < 4; ++r) {
                float s = fmaf(m2r[r], c[r], kn);
                if (s <= thr[r]) {
                    int pix = wid * 16 + quad * 4 + r;     // wave-owned pixel
                    int pos = atomicAdd(&scnt[pix], 1);
                    if (pos < VQ_CAP) slist[pix][pos] = kidx;
                }
            }
        }
        __syncthreads();   // B1: candidates block-visible

        // ---- exact fp32 rescore: 4 lanes/pixel, per-lane only (no shfl here) ----
        {
            const int P   = wid * 16 + (lane >> 2);    // this lane's rescore pixel
            const int sub = lane & 3;
            const int cnt = scnt[P];
            if (cnt > 1) {
                const float* xp = xblk + P;
                if (cnt <= VQ_CAP) {
                    for (int i = sub; i < cnt; i += 4) {
                        const int k = slist[P][i];
                        const float* cr = cbn + (size_t)k * 64;
                        float dot = 0.0f;
                        #pragma unroll 8
                        for (int c = 0; c < 64; ++c)
                            dot = fmaf(xp[(size_t)c * 4096], cr[c], dot);  // R1 order
                        float s = fmaf(m2P, dot, kn2[k]);
                        unsigned long long key =
                            ((unsigned long long)f2ord(s) << 32) | (unsigned)k;
                        atomicMin(&spack[P], key);
                    }
                } else {   // statistically dead overflow: exact scan of all codes
                    for (int k = sub; k < 512; k += 4) {
                        const float* cr = cbn + (size_t)k * 64;
                        float dot = 0.0f;
                        #pragma unroll 8
                        for (int c = 0; c < 64; ++c)
                            dot = fmaf(xp[(size_t)c * 4096], cr[c], dot);
                        float s = fmaf(m2P, dot, kn2[k]);
                        unsigned long long key =
                            ((unsigned long long)f2ord(s) << 32) | (unsigned)k;
                        atomicMin(&spack[P], key);
                    }
                }
            }
        }
        __syncthreads();   // B2: rescore results block-visible

        // ---- read winner (packed key ties break to smallest k; cnt==1 fast path) ----
        const int cntw = scnt[wpix];
        const int bk = (cntw == 1) ? slist[wpix][0]
                                   : (int)(spack[wpix] & 0xFFFFFFFFull);

        if (quad == 0) idxout[rowid * 64 + wpix] = (float)bk;

        // ---- epilogue: codes[b, :, h, wpix] = cbn[bk, :]; lane writes channels
        //      quad*16 .. quad*16+15 ----
        {
            const float4* crow = (const float4*)(cbn + (size_t)bk * 64) + quad * 4;
            float* cp = codes + ((size_t)b << 18) + (h << 6) + wpix;
            #pragma unroll
            for (int q = 0; q < 4; ++q) {
                float4 v = crow[q];
                const int c0 = quad * 16 + q * 4;
                cp[(size_t)(c0 + 0) * 4096] = v.x;
                cp[(size_t)(c0 + 1) * 4096] = v.y;
                cp[(size_t)(c0 + 2) * 4096] = v.z;
                cp[(size_t)(c0 + 3) * 4096] = v.w;
            }
        }
        __syncthreads();   // B3: protect scnt/slist/spack from next row's init
    }
}

extern "C" void kernel_launch(void* const* d_in, const int* in_sizes, int n_in,
                              void* d_out, int out_size, void* d_ws, size_t ws_size,
                              hipStream_t stream) {
    const float* x  = (const float*)d_in[0];   // [32,64,64,64] fp32
    const float* cb = (const float*)d_in[1];   // [512,64] fp32

    float*          cbn  = (float*)d_ws;                       // 128 KB
    unsigned short* cbB  = (unsigned short*)(cbn + 512 * 64);  // 64 KB (frag-linear bf16)
    float*          kn2  = (float*)(cbB + 32768);              // 2 KB
    float*          kn2p = kn2 + 512;                          // 2 KB

    float* codes  = (float*)d_out;                             // 32*64*64*64 floats
    float* idxout = codes + (size_t)32 * 64 * 64 * 64;         // 131072 floats

    cb_prep_kernel<<<512, 64, 0, stream>>>(cb, cbn, cbB, kn2, kn2p);
    vq_mfma_kernel<<<512, 256, 0, stream>>>(x, cbn, cbB, kn2, kn2p, codes, idxout);
}